// Round 2
// baseline (212.002 us; speedup 1.0000x reference)
//
#include <hip/hip_runtime.h>

#define B_ROWS 128
#define T_SAMP 160000
#define NSEC 3

struct Coefs {
  float b0[NSEC], b1[NSEC], b2[NSEC], a1[NSEC], a2[NSEC];
};

__device__ __forceinline__ void load_coefs(const float* __restrict__ sos, Coefs& c) {
#pragma unroll
  for (int s = 0; s < NSEC; ++s) {
    c.b0[s] = sos[s * 6 + 0];
    c.b1[s] = sos[s * 6 + 1];
    c.b2[s] = sos[s * 6 + 2];
    c.a1[s] = sos[s * 6 + 4];
    c.a2[s] = sos[s * 6 + 5];
  }
}

// One DF2T cascade time-step, same op order as the reference.
__device__ __forceinline__ float df2t_step(const Coefs& c, float z[6], float x) {
  float y = x;
#pragma unroll
  for (int s = 0; s < NSEC; ++s) {
    float out = fmaf(c.b0[s], y, z[2 * s]);
    float t0  = fmaf(c.b1[s], y, z[2 * s + 1]);
    z[2 * s]     = fmaf(-c.a1[s], out, t0);
    float t1  = c.b2[s] * y;
    z[2 * s + 1] = fmaf(-c.a2[s], out, t1);
    y = out;
  }
  return y;
}

// Pass 1: zero-state response of each chunk -> final state f[r][c][6]
__global__ __launch_bounds__(256) void pass1_kernel(const float* __restrict__ x,
                                                    const float* __restrict__ sos,
                                                    float* __restrict__ f, int C, int L) {
  int tid = blockIdx.x * blockDim.x + threadIdx.x;
  if (tid >= B_ROWS * C) return;
  int r = tid / C, cc = tid % C;
  Coefs cf; load_coefs(sos, cf);
  float z[6] = {0.f, 0.f, 0.f, 0.f, 0.f, 0.f};
  const float4* xp = reinterpret_cast<const float4*>(x + (size_t)r * T_SAMP + (size_t)cc * L);
  const int n4 = L >> 2;
  // depth-2 register prefetch: next two lines in flight during the 4 serial steps
  float4 v0 = xp[0];
  float4 v1 = (n4 > 1) ? xp[1] : v0;
  for (int i = 0; i < n4; ++i) {
    float4 vn = (i + 2 < n4) ? xp[i + 2] : v1;
    df2t_step(cf, z, v0.x);
    df2t_step(cf, z, v0.y);
    df2t_step(cf, z, v0.z);
    df2t_step(cf, z, v0.w);
    v0 = v1; v1 = vn;
  }
  float* fo = f + (size_t)tid * 6;
#pragma unroll
  for (int k = 0; k < 6; ++k) fo[k] = z[k];
}

// 6x6 matmul, fully unrolled so arrays stay in registers (rule #20).
__device__ __forceinline__ void mat_mul6(float D[36], const float A[36], const float Bm[36]) {
#pragma unroll
  for (int i = 0; i < 6; ++i) {
#pragma unroll
    for (int j = 0; j < 6; ++j) {
      float s = A[i * 6 + 0] * Bm[0 * 6 + j];
#pragma unroll
      for (int k = 1; k < 6; ++k) s = fmaf(A[i * 6 + k], Bm[k * 6 + j], s);
      D[i * 6 + j] = s;
    }
  }
}

__device__ __forceinline__ void mat_copy(float D[36], const float S[36]) {
#pragma unroll
  for (int i = 0; i < 36; ++i) D[i] = S[i];
}

// M = A^e by square-and-multiply (runtime e, constant-indexed arrays -> registers)
__device__ __forceinline__ void mat_pow(float M[36], const float A[36], int e) {
  float P[36], Tm[36];
  mat_copy(P, A);
#pragma unroll
  for (int i = 0; i < 36; ++i) M[i] = 0.0f;
#pragma unroll
  for (int i = 0; i < 6; ++i) M[i * 6 + i] = 1.0f;
  while (e) {
    if (e & 1) { mat_mul6(Tm, M, P); mat_copy(M, Tm); }
    e >>= 1;
    if (e) { mat_mul6(Tm, P, P); mat_copy(P, Tm); }
  }
}

// Middle: per-row boundary scan  z[c+1] = M z[c] + f[c]  (M = A^L), emit z_start[r][c][6].
// One wave per row. Lane l owns chunks [l*seg, (l+1)*seg). Segment-serial reduce,
// 6-level shuffle scan with matrices M^(seg*2^k), then segment re-expand.
__global__ __launch_bounds__(64) void middle_scan(const float* __restrict__ f,
                                                  const float* __restrict__ sos,
                                                  float* __restrict__ zs, int C, int L) {
  const int r = blockIdx.x;
  const int lane = threadIdx.x;
  const int seg = C >> 6;  // C is a multiple of 64
  Coefs cf; load_coefs(sos, cf);

  // Build A by stepping unit basis vectors with x=0 (state map is linear).
  float A[36];
#pragma unroll
  for (int j = 0; j < 6; ++j) {
    float z[6] = {0.f, 0.f, 0.f, 0.f, 0.f, 0.f};
    z[j] = 1.0f;
    df2t_step(cf, z, 0.0f);
#pragma unroll
    for (int i = 0; i < 6; ++i) A[i * 6 + j] = z[i];
  }
  float M[36];
  mat_pow(M, A, L);  // per-chunk transition

  // Segment-serial inclusive reduce from zero state: s = M s + f[c]
  const float* frow = f + (size_t)r * C * 6;
  float s[6] = {0.f, 0.f, 0.f, 0.f, 0.f, 0.f};
  for (int j = 0; j < seg; ++j) {
    const float* fc = frow + (size_t)(lane * seg + j) * 6;
    float zn[6];
#pragma unroll
    for (int i = 0; i < 6; ++i) {
      float acc = fc[i];
#pragma unroll
      for (int k = 0; k < 6; ++k) acc = fmaf(M[i * 6 + k], s[k], acc);
      zn[i] = acc;
    }
#pragma unroll
    for (int i = 0; i < 6; ++i) s[i] = zn[i];
  }

  // Cross-lane inclusive scan; level-k matrix is P = M^(seg*2^k).
  float P[36];
  mat_pow(P, M, seg);
#pragma unroll
  for (int k = 0; k < 6; ++k) {
    float t[6];
#pragma unroll
    for (int i = 0; i < 6; ++i) t[i] = __shfl_up(s[i], 1 << k);
    if (lane >= (1 << k)) {
      float ns[6];
#pragma unroll
      for (int i = 0; i < 6; ++i) {
        float acc = s[i];
#pragma unroll
        for (int kk = 0; kk < 6; ++kk) acc = fmaf(P[i * 6 + kk], t[kk], acc);
        ns[i] = acc;
      }
#pragma unroll
      for (int i = 0; i < 6; ++i) s[i] = ns[i];
    }
    if (k < 5) {
      float Tm[36];
      mat_mul6(Tm, P, P);
      mat_copy(P, Tm);
    }
  }

  // Exclusive shift -> state at each lane's segment start.
  float z[6];
#pragma unroll
  for (int i = 0; i < 6; ++i) {
    float t = __shfl_up(s[i], 1);
    z[i] = (lane == 0) ? 0.0f : t;
  }

  // Re-expand: emit z_start per chunk, step with M.
  float* zrow = zs + (size_t)r * C * 6;
  for (int j = 0; j < seg; ++j) {
    const int c = lane * seg + j;
    const float* fc = frow + (size_t)c * 6;
    float* zo = zrow + (size_t)c * 6;
#pragma unroll
    for (int i = 0; i < 6; ++i) zo[i] = z[i];
    float zn[6];
#pragma unroll
    for (int i = 0; i < 6; ++i) {
      float acc = fc[i];
#pragma unroll
      for (int k = 0; k < 6; ++k) acc = fmaf(M[i * 6 + k], z[k], acc);
      zn[i] = acc;
    }
#pragma unroll
    for (int i = 0; i < 6; ++i) z[i] = zn[i];
  }
}

// Pass 2: re-run each chunk from its exact starting state, write outputs.
__global__ __launch_bounds__(256) void pass2_kernel(const float* __restrict__ x,
                                                    const float* __restrict__ sos,
                                                    const float* __restrict__ zs,
                                                    float* __restrict__ y, int C, int L) {
  int tid = blockIdx.x * blockDim.x + threadIdx.x;
  if (tid >= B_ROWS * C) return;
  int r = tid / C, cc = tid % C;
  Coefs cf; load_coefs(sos, cf);
  float z[6];
  const float* zp0 = zs + (size_t)tid * 6;
#pragma unroll
  for (int k = 0; k < 6; ++k) z[k] = zp0[k];
  const size_t base = (size_t)r * T_SAMP + (size_t)cc * L;
  const float4* xp = reinterpret_cast<const float4*>(x + base);
  float4* yp = reinterpret_cast<float4*>(y + base);
  const int n4 = L >> 2;
  float4 v0 = xp[0];
  float4 v1 = (n4 > 1) ? xp[1] : v0;
  for (int i = 0; i < n4; ++i) {
    float4 vn = (i + 2 < n4) ? xp[i + 2] : v1;
    float4 w;
    w.x = df2t_step(cf, z, v0.x);
    w.y = df2t_step(cf, z, v0.y);
    w.z = df2t_step(cf, z, v0.z);
    w.w = df2t_step(cf, z, v0.w);
    yp[i] = w;
    v0 = v1; v1 = vn;
  }
}

extern "C" void kernel_launch(void* const* d_in, const int* in_sizes, int n_in,
                              void* d_out, int out_size, void* d_ws, size_t ws_size,
                              hipStream_t stream) {
  const float* x = (const float*)d_in[0];
  const float* sos = (const float*)d_in[1];
  float* y = (float*)d_out;

  // C: multiple of 64 (wave-parallel scan), L = T/C multiple of 4, ws-constrained.
  int C = 64;
  const int cand[3] = {1600, 320, 64};
  for (int i = 0; i < 3; ++i) {
    size_t need = (size_t)2 * B_ROWS * cand[i] * 6 * sizeof(float);
    if (need <= ws_size) { C = cand[i]; break; }
  }
  const int L = T_SAMP / C;

  float* f = (float*)d_ws;                  // [B][C][6] zero-state final states
  float* zst = f + (size_t)B_ROWS * C * 6;  // [B][C][6] exact chunk-start states

  const int threads = B_ROWS * C;
  const int blocks = (threads + 255) / 256;
  hipLaunchKernelGGL(pass1_kernel, dim3(blocks), dim3(256), 0, stream, x, sos, f, C, L);
  hipLaunchKernelGGL(middle_scan, dim3(B_ROWS), dim3(64), 0, stream, f, sos, zst, C, L);
  hipLaunchKernelGGL(pass2_kernel, dim3(blocks), dim3(256), 0, stream, x, sos, zst, y, C, L);
}

// Round 3
// 100.534 us; speedup vs baseline: 2.1088x; 2.1088x over previous
//
#include <hip/hip_runtime.h>

#define B_ROWS 128
#define T_SAMP 160000
#define NSEC 3
#define TS 20          // samples per LDS tile
#define NR 5           // float4 staging rounds per tile = 64*TS/4/64
#define ROWSTRIDE 21   // TS+1 (odd) -> conflict-free per-lane row reads

struct Coefs {
  float b0[NSEC], b1[NSEC], b2[NSEC], a1[NSEC], a2[NSEC];
};

__device__ __forceinline__ void load_coefs(const float* __restrict__ sos, Coefs& c) {
#pragma unroll
  for (int s = 0; s < NSEC; ++s) {
    c.b0[s] = sos[s * 6 + 0];
    c.b1[s] = sos[s * 6 + 1];
    c.b2[s] = sos[s * 6 + 2];
    c.a1[s] = sos[s * 6 + 4];
    c.a2[s] = sos[s * 6 + 5];
  }
}

// One DF2T cascade time-step, same op order as the reference.
__device__ __forceinline__ float df2t_step(const Coefs& c, float z[6], float x) {
  float y = x;
#pragma unroll
  for (int s = 0; s < NSEC; ++s) {
    float out = fmaf(c.b0[s], y, z[2 * s]);
    float t0  = fmaf(c.b1[s], y, z[2 * s + 1]);
    z[2 * s]     = fmaf(-c.a1[s], out, t0);
    float t1  = c.b2[s] * y;
    z[2 * s + 1] = fmaf(-c.a2[s], out, t1);
    y = out;
  }
  return y;
}

// Pass 1: zero-state response of each chunk -> final state f[r][c][6].
// One wave per 64 consecutive chunks of a row; LDS-staged coalesced reads.
__global__ __launch_bounds__(64) void pass1_kernel(const float* __restrict__ x,
                                                   const float* __restrict__ sos,
                                                   float* __restrict__ f, int C, int L) {
  __shared__ float Bsh[64 * ROWSTRIDE];
  const int lane = threadIdx.x;
  const int WPR = C >> 6;              // waves per row
  const int r = blockIdx.x / WPR;
  const int c0 = (blockIdx.x % WPR) << 6;
  Coefs cf; load_coefs(sos, cf);

  // Per-round staging maps: flat f4 index q = i*64+lane -> (chunk k, f4 m).
  int lofs[NR], gofs[NR];
#pragma unroll
  for (int i = 0; i < NR; ++i) {
    int q = i * 64 + lane;
    int k = q / NR, m = q - k * NR;
    lofs[i] = k * ROWSTRIDE + m * 4;
    gofs[i] = k * L + m * 4;
  }

  const float* xrow = x + (size_t)r * T_SAMP + (size_t)c0 * L;
  const int ntile = L / TS;
  float4 v[NR];
#pragma unroll
  for (int i = 0; i < NR; ++i) v[i] = *reinterpret_cast<const float4*>(xrow + gofs[i]);

  float z[6] = {0.f, 0.f, 0.f, 0.f, 0.f, 0.f};
  for (int tile = 0; tile < ntile; ++tile) {
    // stage registers -> LDS
#pragma unroll
    for (int i = 0; i < NR; ++i) {
      Bsh[lofs[i] + 0] = v[i].x; Bsh[lofs[i] + 1] = v[i].y;
      Bsh[lofs[i] + 2] = v[i].z; Bsh[lofs[i] + 3] = v[i].w;
    }
    __syncthreads();
    // issue next tile's loads; they fly during compute (T14)
    if (tile + 1 < ntile) {
      const float* src = xrow + (size_t)(tile + 1) * TS;
#pragma unroll
      for (int i = 0; i < NR; ++i) v[i] = *reinterpret_cast<const float4*>(src + gofs[i]);
    }
    // serial IIR on own LDS row
#pragma unroll
    for (int j = 0; j < TS; ++j) df2t_step(cf, z, Bsh[lane * ROWSTRIDE + j]);
    __syncthreads();
  }
  float* fo = f + (size_t)(r * C + c0 + lane) * 6;
#pragma unroll
  for (int k = 0; k < 6; ++k) fo[k] = z[k];
}

// 6x6 matmul, fully unrolled so arrays stay in registers (rule #20).
__device__ __forceinline__ void mat_mul6(float D[36], const float A[36], const float Bm[36]) {
#pragma unroll
  for (int i = 0; i < 6; ++i) {
#pragma unroll
    for (int j = 0; j < 6; ++j) {
      float s = A[i * 6 + 0] * Bm[0 * 6 + j];
#pragma unroll
      for (int k = 1; k < 6; ++k) s = fmaf(A[i * 6 + k], Bm[k * 6 + j], s);
      D[i * 6 + j] = s;
    }
  }
}

__device__ __forceinline__ void mat_copy(float D[36], const float S[36]) {
#pragma unroll
  for (int i = 0; i < 36; ++i) D[i] = S[i];
}

__device__ __forceinline__ void mat_pow(float M[36], const float A[36], int e) {
  float P[36], Tm[36];
  mat_copy(P, A);
#pragma unroll
  for (int i = 0; i < 36; ++i) M[i] = 0.0f;
#pragma unroll
  for (int i = 0; i < 6; ++i) M[i * 6 + i] = 1.0f;
  while (e) {
    if (e & 1) { mat_mul6(Tm, M, P); mat_copy(M, Tm); }
    e >>= 1;
    if (e) { mat_mul6(Tm, P, P); mat_copy(P, Tm); }
  }
}

// Middle: per-row boundary scan  z[c+1] = M z[c] + f[c]  (M = A^L), emit z_start[r][c][6].
__global__ __launch_bounds__(64) void middle_scan(const float* __restrict__ f,
                                                  const float* __restrict__ sos,
                                                  float* __restrict__ zs, int C, int L) {
  const int r = blockIdx.x;
  const int lane = threadIdx.x;
  const int seg = C >> 6;
  Coefs cf; load_coefs(sos, cf);

  float A[36];
#pragma unroll
  for (int j = 0; j < 6; ++j) {
    float z[6] = {0.f, 0.f, 0.f, 0.f, 0.f, 0.f};
    z[j] = 1.0f;
    df2t_step(cf, z, 0.0f);
#pragma unroll
    for (int i = 0; i < 6; ++i) A[i * 6 + j] = z[i];
  }
  float M[36];
  mat_pow(M, A, L);

  const float* frow = f + (size_t)r * C * 6;
  float s[6] = {0.f, 0.f, 0.f, 0.f, 0.f, 0.f};
  for (int j = 0; j < seg; ++j) {
    const float* fc = frow + (size_t)(lane * seg + j) * 6;
    float zn[6];
#pragma unroll
    for (int i = 0; i < 6; ++i) {
      float acc = fc[i];
#pragma unroll
      for (int k = 0; k < 6; ++k) acc = fmaf(M[i * 6 + k], s[k], acc);
      zn[i] = acc;
    }
#pragma unroll
    for (int i = 0; i < 6; ++i) s[i] = zn[i];
  }

  float P[36];
  mat_pow(P, M, seg);
#pragma unroll
  for (int k = 0; k < 6; ++k) {
    float t[6];
#pragma unroll
    for (int i = 0; i < 6; ++i) t[i] = __shfl_up(s[i], 1 << k);
    if (lane >= (1 << k)) {
      float ns[6];
#pragma unroll
      for (int i = 0; i < 6; ++i) {
        float acc = s[i];
#pragma unroll
        for (int kk = 0; kk < 6; ++kk) acc = fmaf(P[i * 6 + kk], t[kk], acc);
        ns[i] = acc;
      }
#pragma unroll
      for (int i = 0; i < 6; ++i) s[i] = ns[i];
    }
    if (k < 5) {
      float Tm[36];
      mat_mul6(Tm, P, P);
      mat_copy(P, Tm);
    }
  }

  float z[6];
#pragma unroll
  for (int i = 0; i < 6; ++i) {
    float t = __shfl_up(s[i], 1);
    z[i] = (lane == 0) ? 0.0f : t;
  }

  float* zrow = zs + (size_t)r * C * 6;
  for (int j = 0; j < seg; ++j) {
    const int c = lane * seg + j;
    const float* fc = frow + (size_t)c * 6;
    float* zo = zrow + (size_t)c * 6;
#pragma unroll
    for (int i = 0; i < 6; ++i) zo[i] = z[i];
    float zn[6];
#pragma unroll
    for (int i = 0; i < 6; ++i) {
      float acc = fc[i];
#pragma unroll
      for (int k = 0; k < 6; ++k) acc = fmaf(M[i * 6 + k], z[k], acc);
      zn[i] = acc;
    }
#pragma unroll
    for (int i = 0; i < 6; ++i) z[i] = zn[i];
  }
}

// Pass 2: re-run each chunk from exact start state; LDS-staged reads AND writes.
__global__ __launch_bounds__(64) void pass2_kernel(const float* __restrict__ x,
                                                   const float* __restrict__ sos,
                                                   const float* __restrict__ zs,
                                                   float* __restrict__ y, int C, int L) {
  __shared__ float Bsh[64 * ROWSTRIDE];
  const int lane = threadIdx.x;
  const int WPR = C >> 6;
  const int r = blockIdx.x / WPR;
  const int c0 = (blockIdx.x % WPR) << 6;
  Coefs cf; load_coefs(sos, cf);

  int lofs[NR], gofs[NR];
#pragma unroll
  for (int i = 0; i < NR; ++i) {
    int q = i * 64 + lane;
    int k = q / NR, m = q - k * NR;
    lofs[i] = k * ROWSTRIDE + m * 4;
    gofs[i] = k * L + m * 4;
  }

  const float* xrow = x + (size_t)r * T_SAMP + (size_t)c0 * L;
  float* yrow = y + (size_t)r * T_SAMP + (size_t)c0 * L;
  const int ntile = L / TS;

  float z[6];
  const float* zp0 = zs + (size_t)(r * C + c0 + lane) * 6;
#pragma unroll
  for (int k = 0; k < 6; ++k) z[k] = zp0[k];

  float4 v[NR];
#pragma unroll
  for (int i = 0; i < NR; ++i) v[i] = *reinterpret_cast<const float4*>(xrow + gofs[i]);

  for (int tile = 0; tile < ntile; ++tile) {
#pragma unroll
    for (int i = 0; i < NR; ++i) {
      Bsh[lofs[i] + 0] = v[i].x; Bsh[lofs[i] + 1] = v[i].y;
      Bsh[lofs[i] + 2] = v[i].z; Bsh[lofs[i] + 3] = v[i].w;
    }
    __syncthreads();
    if (tile + 1 < ntile) {
      const float* src = xrow + (size_t)(tile + 1) * TS;
#pragma unroll
      for (int i = 0; i < NR; ++i) v[i] = *reinterpret_cast<const float4*>(src + gofs[i]);
    }
    // in-place: read sample, write filtered sample back to same slot
#pragma unroll
    for (int j = 0; j < TS; ++j) {
      float out = df2t_step(cf, z, Bsh[lane * ROWSTRIDE + j]);
      Bsh[lane * ROWSTRIDE + j] = out;
    }
    __syncthreads();
    // drain LDS -> dense float4 stores
    float* dst = yrow + (size_t)tile * TS;
#pragma unroll
    for (int i = 0; i < NR; ++i) {
      float4 w;
      w.x = Bsh[lofs[i] + 0]; w.y = Bsh[lofs[i] + 1];
      w.z = Bsh[lofs[i] + 2]; w.w = Bsh[lofs[i] + 3];
      *reinterpret_cast<float4*>(dst + gofs[i]) = w;
    }
    __syncthreads();
  }
}

extern "C" void kernel_launch(void* const* d_in, const int* in_sizes, int n_in,
                              void* d_out, int out_size, void* d_ws, size_t ws_size,
                              hipStream_t stream) {
  const float* x = (const float*)d_in[0];
  const float* sos = (const float*)d_in[1];
  float* y = (float*)d_out;

  // C: multiple of 64, L = T/C multiple of TS(20), ws-constrained.
  int C = 64;
  const int cand[3] = {1600, 320, 64};
  for (int i = 0; i < 3; ++i) {
    size_t need = (size_t)2 * B_ROWS * cand[i] * 6 * sizeof(float);
    if (need <= ws_size) { C = cand[i]; break; }
  }
  const int L = T_SAMP / C;

  float* f = (float*)d_ws;                  // [B][C][6] zero-state final states
  float* zst = f + (size_t)B_ROWS * C * 6;  // [B][C][6] exact chunk-start states

  const int nwaves = B_ROWS * (C >> 6);     // one 64-thread block per wave
  hipLaunchKernelGGL(pass1_kernel, dim3(nwaves), dim3(64), 0, stream, x, sos, f, C, L);
  hipLaunchKernelGGL(middle_scan, dim3(B_ROWS), dim3(64), 0, stream, f, sos, zst, C, L);
  hipLaunchKernelGGL(pass2_kernel, dim3(nwaves), dim3(64), 0, stream, x, sos, zst, y, C, L);
}

// Round 4
// 71.589 us; speedup vs baseline: 2.9614x; 1.4043x over previous
//
#include <hip/hip_runtime.h>

#define B_ROWS 128
#define T_SAMP 160000
#define NSEC 3
#define LCH 20     // samples per chunk (one lane)
#define NRND 5     // float4 staging rounds per wave: 64*20/4/64
#define RST 21     // LDS row stride in floats (odd -> 2-way=free bank access)
#define SUPW 1280  // samples per superchunk (= one wave: 64 chunks * 20)
#define NSUP 125   // superchunks per row: 160000/1280
#define WPB 4      // waves per block
#define NMAT_P 6   // P_k = M^(2^k), k=0..5 (wave scan)
#define NMAT_Q 7   // Q_k = Msup^(2^k), k=0..6 (row scan), Msup = M^64

struct Coefs {
  float b0[NSEC], b1[NSEC], b2[NSEC], a1[NSEC], a2[NSEC];
};

__device__ __forceinline__ void load_coefs(const float* __restrict__ sos, Coefs& c) {
#pragma unroll
  for (int s = 0; s < NSEC; ++s) {
    c.b0[s] = sos[s * 6 + 0];
    c.b1[s] = sos[s * 6 + 1];
    c.b2[s] = sos[s * 6 + 2];
    c.a1[s] = sos[s * 6 + 4];
    c.a2[s] = sos[s * 6 + 5];
  }
}

// One DF2T cascade time-step, same op order as the reference.
__device__ __forceinline__ float df2t_step(const Coefs& c, float z[6], float x) {
  float y = x;
#pragma unroll
  for (int s = 0; s < NSEC; ++s) {
    float out = fmaf(c.b0[s], y, z[2 * s]);
    float t0  = fmaf(c.b1[s], y, z[2 * s + 1]);
    z[2 * s]     = fmaf(-c.a1[s], out, t0);
    float t1  = c.b2[s] * y;
    z[2 * s + 1] = fmaf(-c.a2[s], out, t1);
    y = out;
  }
  return y;
}

// Lane-distributed 6x6 matmul: lane e<36 holds element (e/6, e%6) of each matrix.
__device__ __forceinline__ float dmm6(float a, float b, int i, int j) {
  float s = 0.f;
#pragma unroll
  for (int k = 0; k < 6; ++k)
    s = fmaf(__shfl(a, i * 6 + k), __shfl(b, k * 6 + j), s);
  return s;
}

// Setup: compute transition-matrix powers once.
// mats layout: [0..5]=P_k=M^(2^k) (M=A^20), [6..12]=Q_k=Msup^(2^k) (Msup=M^64).
__global__ __launch_bounds__(64) void setup_kernel(const float* __restrict__ sos,
                                                   float* __restrict__ mats) {
  const int lane = threadIdx.x;
  const int e = (lane < 36) ? lane : 0;
  const int i = e / 6, j = e % 6;
  Coefs cf; load_coefs(sos, cf);

  // Build A locally in every lane (state map is linear; step basis vectors, x=0).
  float A[36];
#pragma unroll
  for (int jc = 0; jc < 6; ++jc) {
    float z[6] = {0.f, 0.f, 0.f, 0.f, 0.f, 0.f};
    z[jc] = 1.0f;
    df2t_step(cf, z, 0.0f);
#pragma unroll
    for (int ic = 0; ic < 6; ++ic) A[ic * 6 + jc] = z[ic];
  }
  float a = A[e];  // distributed: one element per lane

  float a2  = dmm6(a, a, i, j);
  float a4  = dmm6(a2, a2, i, j);
  float a8  = dmm6(a4, a4, i, j);
  float a16 = dmm6(a8, a8, i, j);
  float p[NMAT_P];
  p[0] = dmm6(a16, a4, i, j);  // M = A^20
#pragma unroll
  for (int k = 1; k < NMAT_P; ++k) p[k] = dmm6(p[k - 1], p[k - 1], i, j);
  float q[NMAT_Q];
  q[0] = dmm6(p[5], p[5], i, j);  // Msup = M^64
#pragma unroll
  for (int k = 1; k < NMAT_Q; ++k) q[k] = dmm6(q[k - 1], q[k - 1], i, j);

  if (lane < 36) {
#pragma unroll
    for (int k = 0; k < NMAT_P; ++k) mats[k * 36 + lane] = p[k];
#pragma unroll
    for (int k = 0; k < NMAT_Q; ++k) mats[(NMAT_P + k) * 36 + lane] = q[k];
  }
}

// Pass 1: per superchunk (one wave), zero-state final state -> Fsup[S][6].
__global__ __launch_bounds__(256) void pass1_kernel(const float* __restrict__ x,
                                                    const float* __restrict__ sos,
                                                    const float* __restrict__ mats,
                                                    float* __restrict__ Fsup) {
  __shared__ float Bsh[WPB * 64 * RST + NMAT_P * 36];
  float* Pm = Bsh + WPB * 64 * RST;
  const int tid = threadIdx.x;
  const int w = tid >> 6, lane = tid & 63;
  for (int t = tid; t < NMAT_P * 36; t += 256) Pm[t] = mats[t];
  __syncthreads();

  const int S = blockIdx.x * WPB + w;
  const int r = S / NSUP, s = S - r * NSUP;
  Coefs cf; load_coefs(sos, cf);

  const float* src = x + (size_t)r * T_SAMP + (size_t)s * SUPW;
  float* lds = Bsh + w * 64 * RST;
  // stage 5120B contiguous -> LDS rows (chunk k at row k, stride 21)
#pragma unroll
  for (int i2 = 0; i2 < NRND; ++i2) {
    int q = i2 * 64 + lane, k = q / NRND, m = q - k * NRND;
    float4 v = *reinterpret_cast<const float4*>(src + 4 * q);
    int lo = k * RST + m * 4;
    lds[lo + 0] = v.x; lds[lo + 1] = v.y; lds[lo + 2] = v.z; lds[lo + 3] = v.w;
  }
  __syncthreads();

  float f[6] = {0.f, 0.f, 0.f, 0.f, 0.f, 0.f};
#pragma unroll
  for (int jj = 0; jj < LCH; ++jj) df2t_step(cf, f, lds[lane * RST + jj]);

  // inclusive wave scan of affine f-parts; level-k matrix P_k = M^(2^k)
#pragma unroll
  for (int k = 0; k < 6; ++k) {
    float t[6];
#pragma unroll
    for (int e = 0; e < 6; ++e) t[e] = __shfl_up(f[e], 1 << k);
    if (lane >= (1 << k)) {
      const float* P = Pm + k * 36;
      float nf[6];
#pragma unroll
      for (int e = 0; e < 6; ++e) {
        float acc = f[e];
#pragma unroll
        for (int kk = 0; kk < 6; ++kk) acc = fmaf(P[e * 6 + kk], t[kk], acc);
        nf[e] = acc;
      }
#pragma unroll
      for (int e = 0; e < 6; ++e) f[e] = nf[e];
    }
  }
  if (lane == 63) {
    float* fo = Fsup + (size_t)S * 6;
#pragma unroll
    for (int e = 0; e < 6; ++e) fo[e] = f[e];
  }
}

// Middle: per-row scan over NSUP superchunks: z[s+1] = Msup z[s] + Fsup[s].
// Lane owns superchunks {2*lane, 2*lane+1} (padded to 128 with F=0).
__global__ __launch_bounds__(64) void middle_scan(const float* __restrict__ Fsup,
                                                  const float* __restrict__ mats,
                                                  float* __restrict__ zsup) {
  __shared__ float Qm[NMAT_Q * 36];
  const int r = blockIdx.x, lane = threadIdx.x;
  for (int t = lane; t < NMAT_Q * 36; t += 64) Qm[t] = mats[NMAT_P * 36 + t];
  __syncthreads();

  const float* frow = Fsup + (size_t)r * NSUP * 6;
  float fc[2][6];
#pragma unroll
  for (int jj = 0; jj < 2; ++jj) {
    int c = 2 * lane + jj;
#pragma unroll
    for (int e = 0; e < 6; ++e) fc[jj][e] = (c < NSUP) ? frow[c * 6 + e] : 0.f;
  }
  // serial segment reduce (seed 0): s = Q0 s + fc
  float s[6] = {0.f, 0.f, 0.f, 0.f, 0.f, 0.f};
#pragma unroll
  for (int jj = 0; jj < 2; ++jj) {
    float ns[6];
#pragma unroll
    for (int e = 0; e < 6; ++e) {
      float acc = fc[jj][e];
#pragma unroll
      for (int kk = 0; kk < 6; ++kk) acc = fmaf(Qm[e * 6 + kk], s[kk], acc);
      ns[e] = acc;
    }
#pragma unroll
    for (int e = 0; e < 6; ++e) s[e] = ns[e];
  }
  // shuffle scan; level k combines 2*2^k superchunks -> matrix Q_{k+1}
#pragma unroll
  for (int k = 0; k < 6; ++k) {
    float t[6];
#pragma unroll
    for (int e = 0; e < 6; ++e) t[e] = __shfl_up(s[e], 1 << k);
    if (lane >= (1 << k)) {
      const float* Q = Qm + (k + 1) * 36;
      float ns[6];
#pragma unroll
      for (int e = 0; e < 6; ++e) {
        float acc = s[e];
#pragma unroll
        for (int kk = 0; kk < 6; ++kk) acc = fmaf(Q[e * 6 + kk], t[kk], acc);
        ns[e] = acc;
      }
#pragma unroll
      for (int e = 0; e < 6; ++e) s[e] = ns[e];
    }
  }
  // exclusive shift -> state at start of lane's first superchunk
  float z[6];
#pragma unroll
  for (int e = 0; e < 6; ++e) {
    float t = __shfl_up(s[e], 1);
    z[e] = (lane == 0) ? 0.f : t;
  }
  // emit both start states
  float* zrow = zsup + (size_t)r * NSUP * 6;
#pragma unroll
  for (int jj = 0; jj < 2; ++jj) {
    int c = 2 * lane + jj;
    if (c < NSUP) {
#pragma unroll
      for (int e = 0; e < 6; ++e) zrow[c * 6 + e] = z[e];
    }
    float nz[6];
#pragma unroll
    for (int e = 0; e < 6; ++e) {
      float acc = fc[jj][e];
#pragma unroll
      for (int kk = 0; kk < 6; ++kk) acc = fmaf(Qm[e * 6 + kk], z[kk], acc);
      nz[e] = acc;
    }
#pragma unroll
    for (int e = 0; e < 6; ++e) z[e] = nz[e];
  }
}

// Pass 2: reconstruct exact chunk-start states in-wave, filter, write out.
__global__ __launch_bounds__(256) void pass2_kernel(const float* __restrict__ x,
                                                    const float* __restrict__ sos,
                                                    const float* __restrict__ mats,
                                                    const float* __restrict__ zsup,
                                                    float* __restrict__ y) {
  __shared__ float Bsh[WPB * 64 * RST + NMAT_P * 36];
  float* Pm = Bsh + WPB * 64 * RST;
  const int tid = threadIdx.x;
  const int w = tid >> 6, lane = tid & 63;
  for (int t = tid; t < NMAT_P * 36; t += 256) Pm[t] = mats[t];
  __syncthreads();

  const int S = blockIdx.x * WPB + w;
  const int r = S / NSUP, s = S - r * NSUP;
  Coefs cf; load_coefs(sos, cf);

  const float* src = x + (size_t)r * T_SAMP + (size_t)s * SUPW;
  float* dst = y + (size_t)r * T_SAMP + (size_t)s * SUPW;
  float* lds = Bsh + w * 64 * RST;
  int lofs[NRND];
#pragma unroll
  for (int i2 = 0; i2 < NRND; ++i2) {
    int q = i2 * 64 + lane, k = q / NRND, m = q - k * NRND;
    lofs[i2] = k * RST + m * 4;
    float4 v = *reinterpret_cast<const float4*>(src + 4 * q);
    lds[lofs[i2] + 0] = v.x; lds[lofs[i2] + 1] = v.y;
    lds[lofs[i2] + 2] = v.z; lds[lofs[i2] + 3] = v.w;
  }
  __syncthreads();

  // zero-state response of own chunk (recomputed; VALU has headroom)
  float f[6] = {0.f, 0.f, 0.f, 0.f, 0.f, 0.f};
#pragma unroll
  for (int jj = 0; jj < LCH; ++jj) df2t_step(cf, f, lds[lane * RST + jj]);

  // superchunk start state z0; fold M*z0 into lane 0's f so a zero-seeded
  // scan yields true states:  z_{l+1} = M z_l + f_l,  z_0 = z0.
  float z0[6];
  const float* zp = zsup + (size_t)S * 6;
#pragma unroll
  for (int e = 0; e < 6; ++e) z0[e] = zp[e];
  if (lane == 0) {
    float nf[6];
#pragma unroll
    for (int e = 0; e < 6; ++e) {
      float acc = f[e];
#pragma unroll
      for (int kk = 0; kk < 6; ++kk) acc = fmaf(Pm[e * 6 + kk], z0[kk], acc);
      nf[e] = acc;
    }
#pragma unroll
    for (int e = 0; e < 6; ++e) f[e] = nf[e];
  }
  // inclusive scan (same combine as pass1)
#pragma unroll
  for (int k = 0; k < 6; ++k) {
    float t[6];
#pragma unroll
    for (int e = 0; e < 6; ++e) t[e] = __shfl_up(f[e], 1 << k);
    if (lane >= (1 << k)) {
      const float* P = Pm + k * 36;
      float nf[6];
#pragma unroll
      for (int e = 0; e < 6; ++e) {
        float acc = f[e];
#pragma unroll
        for (int kk = 0; kk < 6; ++kk) acc = fmaf(P[e * 6 + kk], t[kk], acc);
        nf[e] = acc;
      }
#pragma unroll
      for (int e = 0; e < 6; ++e) f[e] = nf[e];
    }
  }
  // exclusive shift -> this lane's chunk start state
  float zs[6];
#pragma unroll
  for (int e = 0; e < 6; ++e) {
    float t = __shfl_up(f[e], 1);
    zs[e] = (lane == 0) ? z0[e] : t;
  }
  // real pass: filter in place in LDS
#pragma unroll
  for (int jj = 0; jj < LCH; ++jj) {
    float out = df2t_step(cf, zs, lds[lane * RST + jj]);
    lds[lane * RST + jj] = out;
  }
  __syncthreads();
  // drain: dense coalesced float4 stores
#pragma unroll
  for (int i2 = 0; i2 < NRND; ++i2) {
    float4 wv;
    wv.x = lds[lofs[i2] + 0]; wv.y = lds[lofs[i2] + 1];
    wv.z = lds[lofs[i2] + 2]; wv.w = lds[lofs[i2] + 3];
    *reinterpret_cast<float4*>(dst + 4 * (i2 * 64 + lane)) = wv;
  }
}

extern "C" void kernel_launch(void* const* d_in, const int* in_sizes, int n_in,
                              void* d_out, int out_size, void* d_ws, size_t ws_size,
                              hipStream_t stream) {
  const float* x = (const float*)d_in[0];
  const float* sos = (const float*)d_in[1];
  float* y = (float*)d_out;

  const int NS = B_ROWS * NSUP;            // 16000 superchunks
  float* Fsup = (float*)d_ws;              // [NS][6]
  float* zsup = Fsup + (size_t)NS * 6;     // [NS][6]
  float* mats = zsup + (size_t)NS * 6;     // [13][36]

  hipLaunchKernelGGL(setup_kernel, dim3(1), dim3(64), 0, stream, sos, mats);
  hipLaunchKernelGGL(pass1_kernel, dim3(NS / WPB), dim3(256), 0, stream, x, sos, mats, Fsup);
  hipLaunchKernelGGL(middle_scan, dim3(B_ROWS), dim3(64), 0, stream, Fsup, mats, zsup);
  hipLaunchKernelGGL(pass2_kernel, dim3(NS / WPB), dim3(256), 0, stream, x, sos, mats, zsup, y);
}

// Round 5
// 64.134 us; speedup vs baseline: 3.3056x; 1.1162x over previous
//
#include <hip/hip_runtime.h>

#define B_ROWS 128
#define T_SAMP 160000
#define NSEC 3
#define LCH 20     // samples per chunk (one lane)
#define NF4 5      // float4 loads per lane (LCH/4)
#define RST 21     // LDS row stride (odd -> conflict-free)
#define SUPW 1280  // samples per superchunk (64 lanes * 20)
#define NSUP 125   // superchunks per row
#define WPB 4      // waves per block
#define NMAT_P 6   // P_k = M^(2^k), M = A^20  (wave scan)
#define NMAT_Q 7   // Q_k = Msup^(2^k), Msup = M^64 (row scan)

struct Coefs {
  float b0[NSEC], b1[NSEC], b2[NSEC], a1[NSEC], a2[NSEC];
};

__device__ __forceinline__ void load_coefs(const float* __restrict__ sos, Coefs& c) {
#pragma unroll
  for (int s = 0; s < NSEC; ++s) {
    c.b0[s] = sos[s * 6 + 0];
    c.b1[s] = sos[s * 6 + 1];
    c.b2[s] = sos[s * 6 + 2];
    c.a1[s] = sos[s * 6 + 4];
    c.a2[s] = sos[s * 6 + 5];
  }
}

// One DF2T cascade time-step, same op order as the reference.
__device__ __forceinline__ float df2t_step(const Coefs& c, float z[6], float x) {
  float y = x;
#pragma unroll
  for (int s = 0; s < NSEC; ++s) {
    float out = fmaf(c.b0[s], y, z[2 * s]);
    float t0  = fmaf(c.b1[s], y, z[2 * s + 1]);
    z[2 * s]     = fmaf(-c.a1[s], out, t0);
    float t1  = c.b2[s] * y;
    z[2 * s + 1] = fmaf(-c.a2[s], out, t1);
    y = out;
  }
  return y;
}

// Affine combine: f := f + P * t, exploiting 2x2-block lower-triangular P
// (cascade: section i depends only on sections <= i). 24 FMAs.
__device__ __forceinline__ void tri_combine(float f[6], const float* __restrict__ P,
                                            const float t[6]) {
  float nf[6];
#pragma unroll
  for (int e = 0; e < 6; ++e) {
    float acc = f[e];
    const int kmax = ((e >> 1) << 1) + 2;
#pragma unroll
    for (int kk = 0; kk < 6; ++kk)
      if (kk < kmax) acc = fmaf(P[e * 6 + kk], t[kk], acc);
    nf[e] = acc;
  }
#pragma unroll
  for (int e = 0; e < 6; ++e) f[e] = nf[e];
}

// Lane-distributed 6x6 matmul: lane e<36 holds element (e/6, e%6).
__device__ __forceinline__ float dmm6(float a, float b, int i, int j) {
  float s = 0.f;
#pragma unroll
  for (int k = 0; k < 6; ++k)
    s = fmaf(__shfl(a, i * 6 + k), __shfl(b, k * 6 + j), s);
  return s;
}

// Setup: mats[0..5]=P_k=M^(2^k) (M=A^20), mats[6..12]=Q_k=Msup^(2^k) (Msup=M^64).
__global__ __launch_bounds__(64) void setup_kernel(const float* __restrict__ sos,
                                                   float* __restrict__ mats) {
  const int lane = threadIdx.x;
  const int e = (lane < 36) ? lane : 0;
  const int i = e / 6, j = e % 6;
  Coefs cf; load_coefs(sos, cf);

  float A[36];
#pragma unroll
  for (int jc = 0; jc < 6; ++jc) {
    float z[6] = {0.f, 0.f, 0.f, 0.f, 0.f, 0.f};
    z[jc] = 1.0f;
    df2t_step(cf, z, 0.0f);
#pragma unroll
    for (int ic = 0; ic < 6; ++ic) A[ic * 6 + jc] = z[ic];
  }
  float a = A[e];

  float a2  = dmm6(a, a, i, j);
  float a4  = dmm6(a2, a2, i, j);
  float a8  = dmm6(a4, a4, i, j);
  float a16 = dmm6(a8, a8, i, j);
  float p[NMAT_P];
  p[0] = dmm6(a16, a4, i, j);  // M = A^20
#pragma unroll
  for (int k = 1; k < NMAT_P; ++k) p[k] = dmm6(p[k - 1], p[k - 1], i, j);
  float q[NMAT_Q];
  q[0] = dmm6(p[5], p[5], i, j);  // Msup = M^64
#pragma unroll
  for (int k = 1; k < NMAT_Q; ++k) q[k] = dmm6(q[k - 1], q[k - 1], i, j);

  if (lane < 36) {
#pragma unroll
    for (int k = 0; k < NMAT_P; ++k) mats[k * 36 + lane] = p[k];
#pragma unroll
    for (int k = 0; k < NMAT_Q; ++k) mats[(NMAT_P + k) * 36 + lane] = q[k];
  }
}

// Pass 1: register-direct. Lane loads its 20 contiguous samples, computes
// zero-state final, wave-scans, lane 63 writes superchunk final.
__global__ __launch_bounds__(256) void pass1_kernel(const float* __restrict__ x,
                                                    const float* __restrict__ sos,
                                                    const float* __restrict__ mats,
                                                    float* __restrict__ Fsup) {
  __shared__ float Pm[NMAT_P * 36];
  const int tid = threadIdx.x;
  const int w = tid >> 6, lane = tid & 63;
  for (int t = tid; t < NMAT_P * 36; t += 256) Pm[t] = mats[t];  // overlaps v-loads

  const int S = blockIdx.x * WPB + w;
  const int r = S / NSUP, s = S - r * NSUP;
  Coefs cf; load_coefs(sos, cf);

  const float4* src = reinterpret_cast<const float4*>(
      x + (size_t)r * T_SAMP + (size_t)s * SUPW + lane * LCH);
  float4 v[NF4];
#pragma unroll
  for (int i = 0; i < NF4; ++i) v[i] = src[i];

  float f[6] = {0.f, 0.f, 0.f, 0.f, 0.f, 0.f};
#pragma unroll
  for (int i = 0; i < NF4; ++i) {
    df2t_step(cf, f, v[i].x); df2t_step(cf, f, v[i].y);
    df2t_step(cf, f, v[i].z); df2t_step(cf, f, v[i].w);
  }
  __syncthreads();  // Pm ready

#pragma unroll
  for (int k = 0; k < 6; ++k) {
    float t[6];
#pragma unroll
    for (int e = 0; e < 6; ++e) t[e] = __shfl_up(f[e], 1 << k);
    if (lane >= (1 << k)) tri_combine(f, Pm + k * 36, t);
  }
  if (lane == 63) {
    float* fo = Fsup + (size_t)S * 6;
#pragma unroll
    for (int e = 0; e < 6; ++e) fo[e] = f[e];
  }
}

// Middle: per-row scan over NSUP superchunks: z[s+1] = Msup z[s] + Fsup[s].
__global__ __launch_bounds__(64) void middle_scan(const float* __restrict__ Fsup,
                                                  const float* __restrict__ mats,
                                                  float* __restrict__ zsup) {
  __shared__ float Qm[NMAT_Q * 36];
  const int r = blockIdx.x, lane = threadIdx.x;
  for (int t = lane; t < NMAT_Q * 36; t += 64) Qm[t] = mats[NMAT_P * 36 + t];
  __syncthreads();

  const float* frow = Fsup + (size_t)r * NSUP * 6;
  float fc[2][6];
#pragma unroll
  for (int jj = 0; jj < 2; ++jj) {
    int c = 2 * lane + jj;
#pragma unroll
    for (int e = 0; e < 6; ++e) fc[jj][e] = (c < NSUP) ? frow[c * 6 + e] : 0.f;
  }
  float s[6] = {0.f, 0.f, 0.f, 0.f, 0.f, 0.f};
#pragma unroll
  for (int jj = 0; jj < 2; ++jj) {
    float ns[6];
#pragma unroll
    for (int e = 0; e < 6; ++e) {
      float acc = fc[jj][e];
#pragma unroll
      for (int kk = 0; kk < 6; ++kk) acc = fmaf(Qm[e * 6 + kk], s[kk], acc);
      ns[e] = acc;
    }
#pragma unroll
    for (int e = 0; e < 6; ++e) s[e] = ns[e];
  }
#pragma unroll
  for (int k = 0; k < 6; ++k) {
    float t[6];
#pragma unroll
    for (int e = 0; e < 6; ++e) t[e] = __shfl_up(s[e], 1 << k);
    if (lane >= (1 << k)) tri_combine(s, Qm + (k + 1) * 36, t);
  }
  float z[6];
#pragma unroll
  for (int e = 0; e < 6; ++e) {
    float t = __shfl_up(s[e], 1);
    z[e] = (lane == 0) ? 0.f : t;
  }
  float* zrow = zsup + (size_t)r * NSUP * 6;
#pragma unroll
  for (int jj = 0; jj < 2; ++jj) {
    int c = 2 * lane + jj;
    if (c < NSUP) {
#pragma unroll
      for (int e = 0; e < 6; ++e) zrow[c * 6 + e] = z[e];
    }
    float nz[6];
#pragma unroll
    for (int e = 0; e < 6; ++e) {
      float acc = fc[jj][e];
#pragma unroll
      for (int kk = 0; kk < 6; ++kk) acc = fmaf(Qm[e * 6 + kk], z[kk], acc);
      nz[e] = acc;
    }
#pragma unroll
    for (int e = 0; e < 6; ++e) z[e] = nz[e];
  }
}

// Pass 2: register-direct loads, in-register zero-state pre-pass + scan +
// true filter; LDS used only to transpose outputs for dense float4 stores.
__global__ __launch_bounds__(256) void pass2_kernel(const float* __restrict__ x,
                                                    const float* __restrict__ sos,
                                                    const float* __restrict__ mats,
                                                    const float* __restrict__ zsup,
                                                    float* __restrict__ y) {
  __shared__ float Bsh[WPB * 64 * RST];
  __shared__ float Pm[NMAT_P * 36];
  const int tid = threadIdx.x;
  const int w = tid >> 6, lane = tid & 63;
  for (int t = tid; t < NMAT_P * 36; t += 256) Pm[t] = mats[t];

  const int S = blockIdx.x * WPB + w;
  const int r = S / NSUP, s = S - r * NSUP;
  Coefs cf; load_coefs(sos, cf);

  const size_t base = (size_t)r * T_SAMP + (size_t)s * SUPW;
  const float4* src = reinterpret_cast<const float4*>(x + base + lane * LCH);
  float4 v[NF4];
#pragma unroll
  for (int i = 0; i < NF4; ++i) v[i] = src[i];

  float z0[6];
  const float* zp = zsup + (size_t)S * 6;
#pragma unroll
  for (int e = 0; e < 6; ++e) z0[e] = zp[e];

  // zero-state pre-pass (registers reused by the true pass below)
  float f[6] = {0.f, 0.f, 0.f, 0.f, 0.f, 0.f};
#pragma unroll
  for (int i = 0; i < NF4; ++i) {
    df2t_step(cf, f, v[i].x); df2t_step(cf, f, v[i].y);
    df2t_step(cf, f, v[i].z); df2t_step(cf, f, v[i].w);
  }
  __syncthreads();  // Pm ready

  // fold M*z0 into lane 0's f so a zero-seeded scan yields true states
  if (lane == 0) tri_combine(f, Pm, z0);
#pragma unroll
  for (int k = 0; k < 6; ++k) {
    float t[6];
#pragma unroll
    for (int e = 0; e < 6; ++e) t[e] = __shfl_up(f[e], 1 << k);
    if (lane >= (1 << k)) tri_combine(f, Pm + k * 36, t);
  }
  float zs[6];
#pragma unroll
  for (int e = 0; e < 6; ++e) {
    float t = __shfl_up(f[e], 1);
    zs[e] = (lane == 0) ? z0[e] : t;
  }

  // true filter pass; outputs -> LDS rows for dense drain
  float* lds = Bsh + w * 64 * RST;
#pragma unroll
  for (int i = 0; i < NF4; ++i) {
    lds[lane * RST + 4 * i + 0] = df2t_step(cf, zs, v[i].x);
    lds[lane * RST + 4 * i + 1] = df2t_step(cf, zs, v[i].y);
    lds[lane * RST + 4 * i + 2] = df2t_step(cf, zs, v[i].z);
    lds[lane * RST + 4 * i + 3] = df2t_step(cf, zs, v[i].w);
  }
  __syncthreads();

  float* dst = y + base;
#pragma unroll
  for (int i2 = 0; i2 < NF4; ++i2) {
    int q = i2 * 64 + lane, k = q / NF4, m = q - k * NF4;
    float4 wv;
    wv.x = lds[k * RST + m * 4 + 0]; wv.y = lds[k * RST + m * 4 + 1];
    wv.z = lds[k * RST + m * 4 + 2]; wv.w = lds[k * RST + m * 4 + 3];
    *reinterpret_cast<float4*>(dst + 4 * q) = wv;
  }
}

extern "C" void kernel_launch(void* const* d_in, const int* in_sizes, int n_in,
                              void* d_out, int out_size, void* d_ws, size_t ws_size,
                              hipStream_t stream) {
  const float* x = (const float*)d_in[0];
  const float* sos = (const float*)d_in[1];
  float* y = (float*)d_out;

  const int NS = B_ROWS * NSUP;            // 16000 superchunks
  float* Fsup = (float*)d_ws;              // [NS][6]
  float* zsup = Fsup + (size_t)NS * 6;     // [NS][6]
  float* mats = zsup + (size_t)NS * 6;     // [13][36]

  hipLaunchKernelGGL(setup_kernel, dim3(1), dim3(64), 0, stream, sos, mats);
  hipLaunchKernelGGL(pass1_kernel, dim3(NS / WPB), dim3(256), 0, stream, x, sos, mats, Fsup);
  hipLaunchKernelGGL(middle_scan, dim3(B_ROWS), dim3(64), 0, stream, Fsup, mats, zsup);
  hipLaunchKernelGGL(pass2_kernel, dim3(NS / WPB), dim3(256), 0, stream, x, sos, mats, zsup, y);
}